// Round 10
// baseline (1560.728 us; speedup 1.0000x reference)
//
#include <hip/hip_runtime.h>

typedef __bf16 bf16x8 __attribute__((ext_vector_type(8)));
typedef float f32x4 __attribute__((ext_vector_type(4)));

union U8 { uint4 u; bf16x8 b; };

__device__ inline float bf16f(unsigned short h) {
    return __uint_as_float(((unsigned)h) << 16);
}

__device__ inline unsigned short f32_to_bf16_rn(float f) {
    unsigned u = __float_as_uint(f);
    unsigned rounding = 0x7FFFu + ((u >> 16) & 1u);
    u += rounding;
    return (unsigned short)(u >> 16);
}

__device__ inline double wsum(double v) {
    #pragma unroll
    for (int m = 32; m; m >>= 1) v += __shfl_xor(v, m, 64);
    return v;
}
__device__ inline double wsum32(double v) {   // reduce within each 32-lane half
    #pragma unroll
    for (int m = 16; m; m >>= 1) v += __shfl_xor(v, m, 64);
    return v;
}
__device__ inline double wmin(double v) {
    #pragma unroll
    for (int m = 32; m; m >>= 1) v = fmin(v, __shfl_xor(v, m, 64));
    return v;
}
__device__ inline double wmax(double v) {
    #pragma unroll
    for (int m = 32; m; m >>= 1) v = fmax(v, __shfl_xor(v, m, 64));
    return v;
}

#define AS1C(p) ((const __attribute__((address_space(1))) void*)(p))
#define AS3(p)  ((__attribute__((address_space(3))) void*)(p))

// ---------------------------------------------------------------------------
// Kernel 0: pre-split fp32 -> 3 bf16 planes (h+m+l) for X and W.
// ---------------------------------------------------------------------------
__global__ __launch_bounds__(256) void split_kernel(
    const float* __restrict__ X, const float* __restrict__ W,
    unsigned short* __restrict__ Xh, unsigned short* __restrict__ Xm, unsigned short* __restrict__ Xl,
    unsigned short* __restrict__ Wh, unsigned short* __restrict__ Wm, unsigned short* __restrict__ Wl)
{
    size_t i4 = (size_t)blockIdx.x * 256 + threadIdx.x;   // float4 index, total 3145728
    const float* src; unsigned short *ph, *pm, *pl; size_t off4;
    if (i4 < 1048576) { src = X; ph = Xh; pm = Xm; pl = Xl; off4 = i4; }
    else              { src = W; ph = Wh; pm = Wm; pl = Wl; off4 = i4 - 1048576; }

    float4 v = ((const float4*)src)[off4];
    ushort4 h, m, l;
    float r1;
    h.x = f32_to_bf16_rn(v.x); r1 = v.x - bf16f(h.x);
    m.x = f32_to_bf16_rn(r1);  l.x = f32_to_bf16_rn(r1 - bf16f(m.x));
    h.y = f32_to_bf16_rn(v.y); r1 = v.y - bf16f(h.y);
    m.y = f32_to_bf16_rn(r1);  l.y = f32_to_bf16_rn(r1 - bf16f(m.y));
    h.z = f32_to_bf16_rn(v.z); r1 = v.z - bf16f(h.z);
    m.z = f32_to_bf16_rn(r1);  l.z = f32_to_bf16_rn(r1 - bf16f(m.z));
    h.w = f32_to_bf16_rn(v.w); r1 = v.w - bf16f(h.w);
    m.w = f32_to_bf16_rn(r1);  l.w = f32_to_bf16_rn(r1 - bf16f(m.w));

    ((ushort4*)ph)[off4] = h;
    ((ushort4*)pm)[off4] = m;
    ((ushort4*)pl)[off4] = l;
}

// ---------------------------------------------------------------------------
// Kernel 1 (v4): 6-plane bf16 GEMM, 128x64 tiles -> 1024 blocks, 36 KB LDS
// -> 4 blocks/CU. Single-buffer global_load_lds width-16, 2-barrier K-loop.
// ---------------------------------------------------------------------------
__global__ __launch_bounds__(256) void gemm_64(
    const unsigned short* __restrict__ Xh, const unsigned short* __restrict__ Xm,
    const unsigned short* __restrict__ Xl,
    const unsigned short* __restrict__ Wh, const unsigned short* __restrict__ Wm,
    const unsigned short* __restrict__ Wl,
    const float* __restrict__ biasf, float* __restrict__ M)
{
    const int K = 2048, N = 4096;
    __shared__ unsigned short S[18432];   // 36 KB

    int tid  = threadIdx.x;
    int id   = blockIdx.x;                 // 0..1023
    int c    = id & 7;                     // XCD (hw round-robins id%8)
    int sid  = id >> 3;                    // 0..127
    int bx   = c * 8 + (sid & 7);          // 0..63
    int by   = sid >> 3;                   // 0..15
    int m0   = by * 128;
    int n0   = bx * 64;

    int wave = tid >> 6;
    int lane = tid & 63;
    int l16  = lane & 15;
    int quad = lane >> 4;
    int wm   = wave * 32;

    const unsigned short* gpA[3];
    const unsigned short* gpB[3];
    gpA[0] = Xh + (size_t)m0 * K;
    gpA[1] = Xm + (size_t)m0 * K;
    gpA[2] = Xl + (size_t)m0 * K;
    gpB[0] = Wh + (size_t)n0 * K;
    gpB[1] = Wm + (size_t)n0 * K;
    gpB[2] = Wl + (size_t)n0 * K;

    int rA = lane >> 2;              // 0..15
    int cA = (lane & 3) << 3;        // ushort col offset 0,8,16,24

    f32x4 acc[2][4];
    #pragma unroll
    for (int mi = 0; mi < 2; ++mi)
        #pragma unroll
        for (int ni = 0; ni < 4; ++ni)
            acc[mi][ni] = f32x4{0.f, 0.f, 0.f, 0.f};

    for (int k0 = 0; k0 < K; k0 += 32) {
        __syncthreads();
        #pragma unroll
        for (int p = 0; p < 3; ++p) {
            #pragma unroll
            for (int q = 0; q < 2; ++q) {
                const unsigned short* g = gpA[p] + (size_t)(32 * wave + 16 * q + rA) * K + k0 + cA;
                char* l = (char*)S + p * 8192 + wave * 2048 + q * 1024;
                __builtin_amdgcn_global_load_lds(AS1C(g), AS3(l), 16, 0, 0);
            }
            {
                const unsigned short* g = gpB[p] + (size_t)(16 * wave + rA) * K + k0 + cA;
                char* l = (char*)S + 24576 + p * 4096 + wave * 1024;
                __builtin_amdgcn_global_load_lds(AS1C(g), AS3(l), 16, 0, 0);
            }
        }
        __syncthreads();

        U8 ah[2], am[2], al[2], bh[4], bm[4], bl[4];
        #pragma unroll
        for (int mi = 0; mi < 2; ++mi) {
            int ro = (wm + mi * 16 + l16) * 32 + quad * 8;
            ah[mi].u = *(const uint4*)&S[ro];
            am[mi].u = *(const uint4*)&S[4096 + ro];
            al[mi].u = *(const uint4*)&S[8192 + ro];
        }
        #pragma unroll
        for (int ni = 0; ni < 4; ++ni) {
            int ro = (ni * 16 + l16) * 32 + quad * 8;
            bh[ni].u = *(const uint4*)&S[12288 + ro];
            bm[ni].u = *(const uint4*)&S[14336 + ro];
            bl[ni].u = *(const uint4*)&S[16384 + ro];
        }

        #pragma unroll
        for (int mi = 0; mi < 2; ++mi)
            #pragma unroll
            for (int ni = 0; ni < 4; ++ni) {
                acc[mi][ni] = __builtin_amdgcn_mfma_f32_16x16x32_bf16(
                    al[mi].b, bh[ni].b, acc[mi][ni], 0, 0, 0);
                acc[mi][ni] = __builtin_amdgcn_mfma_f32_16x16x32_bf16(
                    ah[mi].b, bl[ni].b, acc[mi][ni], 0, 0, 0);
                acc[mi][ni] = __builtin_amdgcn_mfma_f32_16x16x32_bf16(
                    am[mi].b, bm[ni].b, acc[mi][ni], 0, 0, 0);
                acc[mi][ni] = __builtin_amdgcn_mfma_f32_16x16x32_bf16(
                    am[mi].b, bh[ni].b, acc[mi][ni], 0, 0, 0);
                acc[mi][ni] = __builtin_amdgcn_mfma_f32_16x16x32_bf16(
                    ah[mi].b, bm[ni].b, acc[mi][ni], 0, 0, 0);
                acc[mi][ni] = __builtin_amdgcn_mfma_f32_16x16x32_bf16(
                    ah[mi].b, bh[ni].b, acc[mi][ni], 0, 0, 0);
            }
    }

    #pragma unroll
    for (int ni = 0; ni < 4; ++ni) {
        int col = n0 + ni * 16 + l16;
        float bv = biasf[col];
        #pragma unroll
        for (int mi = 0; mi < 2; ++mi) {
            int row = m0 + wm + mi * 16 + quad * 4;
            #pragma unroll
            for (int r = 0; r < 4; ++r)
                M[(size_t)(row + r) * N + col] = acc[mi][ni][r] + bv;
        }
    }
}

// ---------------------------------------------------------------------------
// Kernel 1-fallback: round-3 in-kernel split GEMM (used only if ws too small).
// ---------------------------------------------------------------------------
__global__ __launch_bounds__(256) void gemm_bt(const float* __restrict__ Xf,
                                               const float* __restrict__ Wf,
                                               const float* __restrict__ biasf,
                                               float* __restrict__ M)
{
    const int K = 2048, N = 4096;
    __shared__ unsigned short AsH[128][32];
    __shared__ unsigned short AsM[128][32];
    __shared__ unsigned short AsL[128][32];
    __shared__ unsigned short BsH[128][32];
    __shared__ unsigned short BsM[128][32];
    __shared__ unsigned short BsL[128][32];

    int tid  = threadIdx.x;
    int m0   = blockIdx.y * 128;
    int n0   = blockIdx.x * 128;
    int wid  = tid >> 6;
    int lane = tid & 63;
    int wm   = (wid >> 1) * 64;
    int wn   = (wid & 1) * 64;
    int l16  = lane & 15;
    int quad = lane >> 4;

    f32x4 acc[4][4];
    #pragma unroll
    for (int mi = 0; mi < 4; ++mi)
        #pragma unroll
        for (int ni = 0; ni < 4; ++ni)
            acc[mi][ni] = f32x4{0.f, 0.f, 0.f, 0.f};

    for (int k0 = 0; k0 < K; k0 += 32) {
        #pragma unroll
        for (int s = 0; s < 4; ++s) {
            int c  = tid + s * 256;
            int r  = c >> 3;
            int kc = (c & 7) << 2;
            {
                float4 v = *(const float4*)&Xf[(size_t)(m0 + r) * K + k0 + kc];
                ushort4 h, mm_, l; float r1;
                h.x = f32_to_bf16_rn(v.x); r1 = v.x - bf16f(h.x);
                mm_.x = f32_to_bf16_rn(r1); l.x = f32_to_bf16_rn(r1 - bf16f(mm_.x));
                h.y = f32_to_bf16_rn(v.y); r1 = v.y - bf16f(h.y);
                mm_.y = f32_to_bf16_rn(r1); l.y = f32_to_bf16_rn(r1 - bf16f(mm_.y));
                h.z = f32_to_bf16_rn(v.z); r1 = v.z - bf16f(h.z);
                mm_.z = f32_to_bf16_rn(r1); l.z = f32_to_bf16_rn(r1 - bf16f(mm_.z));
                h.w = f32_to_bf16_rn(v.w); r1 = v.w - bf16f(h.w);
                mm_.w = f32_to_bf16_rn(r1); l.w = f32_to_bf16_rn(r1 - bf16f(mm_.w));
                *(ushort4*)&AsH[r][kc] = h; *(ushort4*)&AsM[r][kc] = mm_; *(ushort4*)&AsL[r][kc] = l;
            }
            {
                float4 v = *(const float4*)&Wf[(size_t)(n0 + r) * K + k0 + kc];
                ushort4 h, mm_, l; float r1;
                h.x = f32_to_bf16_rn(v.x); r1 = v.x - bf16f(h.x);
                mm_.x = f32_to_bf16_rn(r1); l.x = f32_to_bf16_rn(r1 - bf16f(mm_.x));
                h.y = f32_to_bf16_rn(v.y); r1 = v.y - bf16f(h.y);
                mm_.y = f32_to_bf16_rn(r1); l.y = f32_to_bf16_rn(r1 - bf16f(mm_.y));
                h.z = f32_to_bf16_rn(v.z); r1 = v.z - bf16f(h.z);
                mm_.z = f32_to_bf16_rn(r1); l.z = f32_to_bf16_rn(r1 - bf16f(mm_.z));
                h.w = f32_to_bf16_rn(v.w); r1 = v.w - bf16f(h.w);
                mm_.w = f32_to_bf16_rn(r1); l.w = f32_to_bf16_rn(r1 - bf16f(mm_.w));
                *(ushort4*)&BsH[r][kc] = h; *(ushort4*)&BsM[r][kc] = mm_; *(ushort4*)&BsL[r][kc] = l;
            }
        }
        __syncthreads();

        U8 ah[4], am[4], al[4], bh[4], bm[4], bl[4];
        #pragma unroll
        for (int mi = 0; mi < 4; ++mi) {
            ah[mi].u = *(const uint4*)&AsH[wm + mi * 16 + l16][quad * 8];
            am[mi].u = *(const uint4*)&AsM[wm + mi * 16 + l16][quad * 8];
            al[mi].u = *(const uint4*)&AsL[wm + mi * 16 + l16][quad * 8];
        }
        #pragma unroll
        for (int ni = 0; ni < 4; ++ni) {
            bh[ni].u = *(const uint4*)&BsH[wn + ni * 16 + l16][quad * 8];
            bm[ni].u = *(const uint4*)&BsM[wn + ni * 16 + l16][quad * 8];
            bl[ni].u = *(const uint4*)&BsL[wn + ni * 16 + l16][quad * 8];
        }

        #pragma unroll
        for (int mi = 0; mi < 4; ++mi)
            #pragma unroll
            for (int ni = 0; ni < 4; ++ni) {
                acc[mi][ni] = __builtin_amdgcn_mfma_f32_16x16x32_bf16(al[mi].b, bh[ni].b, acc[mi][ni], 0, 0, 0);
                acc[mi][ni] = __builtin_amdgcn_mfma_f32_16x16x32_bf16(ah[mi].b, bl[ni].b, acc[mi][ni], 0, 0, 0);
                acc[mi][ni] = __builtin_amdgcn_mfma_f32_16x16x32_bf16(am[mi].b, bm[ni].b, acc[mi][ni], 0, 0, 0);
                acc[mi][ni] = __builtin_amdgcn_mfma_f32_16x16x32_bf16(am[mi].b, bh[ni].b, acc[mi][ni], 0, 0, 0);
                acc[mi][ni] = __builtin_amdgcn_mfma_f32_16x16x32_bf16(ah[mi].b, bm[ni].b, acc[mi][ni], 0, 0, 0);
                acc[mi][ni] = __builtin_amdgcn_mfma_f32_16x16x32_bf16(ah[mi].b, bh[ni].b, acc[mi][ni], 0, 0, 0);
            }
        __syncthreads();
    }

    #pragma unroll
    for (int ni = 0; ni < 4; ++ni) {
        int col = n0 + wn + ni * 16 + l16;
        float bv = biasf[col];
        #pragma unroll
        for (int mi = 0; mi < 4; ++mi) {
            int row = m0 + wm + mi * 16 + quad * 4;
            #pragma unroll
            for (int r = 0; r < 4; ++r)
                M[(size_t)(row + r) * N + col] = acc[mi][ni][r] + bv;
        }
    }
}

// ---------------------------------------------------------------------------
// Kernel 2 (v5): register-resident fp64 Householder tridiag, occupancy-tuned.
// LDS cut to ~6.8 KB via 4-phase 16-row staging (-> ~16 blocks/CU, 4 waves/
// SIMD, __launch_bounds__(64,4)); k-loop split: k<32 full-width 64, k>=32
// width-32 static (u/w structurally zero below) -> ~30% less f64 VALU work.
// ---------------------------------------------------------------------------
__global__ __launch_bounds__(64, 4) void tridiag_kernel(const float* __restrict__ M,
                                                        const float* __restrict__ regf,
                                                        double* __restrict__ trid)
{
    __shared__ float Ms[16][65];                       // 4.2 KB staging chunk
    __shared__ __align__(16) double rowb[64];
    __shared__ __align__(16) double ubuf[64];
    __shared__ __align__(16) double wbuf[64];
    __shared__ double dbuf[64];
    __shared__ double ebuf[64];

    int g = blockIdx.x;
    int t = threadIdx.x;
    const float* Mg = M + (size_t)g * 4096;

    double A[64];                                      // row t, register-resident
    #pragma unroll
    for (int j = 0; j < 64; ++j) A[j] = 0.0;

    // 4-phase staging + symmetrize: A[j] = 0.5*(M[t][j] + M[j][t])
    #pragma unroll
    for (int ph = 0; ph < 4; ++ph) {
        #pragma unroll
        for (int r = 0; r < 16; ++r)
            Ms[r][t] = Mg[(ph * 16 + r) * 64 + t];     // coalesced
        __syncthreads();
        #pragma unroll
        for (int jj = 0; jj < 16; ++jj)                // column part: M[j][t]
            A[ph * 16 + jj] += 0.5 * (double)Ms[jj][t];
        if ((t >> 4) == ph) {                          // row part: M[t][j]
            int tr = t & 15;
            #pragma unroll
            for (int j = 0; j < 64; ++j)
                A[j] += 0.5 * (double)Ms[tr][j];
        }
        __syncthreads();
    }
    double regv = (double)regf[0];
    #pragma unroll
    for (int j = 0; j < 64; ++j)
        A[j] += (j == t) ? regv : 0.0;

    // ---- loop 1: k = 0..31, full width ----
    #pragma unroll 1
    for (int k = 0; k < 32; ++k) {
        if (t == k) {
            #pragma unroll
            for (int j = 0; j < 32; ++j)
                *(double2*)&rowb[2 * j] = double2{A[2 * j], A[2 * j + 1]};
        }
        __syncthreads();

        double s0 = 0.0, s1 = 0.0;
        #pragma unroll
        for (int j = 0; j < 64; ++j) {
            double aj = (j > k) ? A[j] : 0.0;
            if (j & 1) s1 += aj * aj; else s0 += aj * aj;
        }
        double sigma = __shfl(s0 + s1, k, 64);
        double x  = rowb[t];
        double x1 = __shfl(x, k + 1, 64);

        double alpha = 0.0, u = 0.0, w = 0.0, Kh = 1.0;
        bool run = (sigma > 1e-300);
        if (run) {
            double sq = sqrt(sigma);
            alpha = (x1 >= 0.0) ? -sq : sq;
            Kh = sigma - x1 * alpha;
            u = (t == k + 1) ? (x - alpha) : ((t > k) ? x : 0.0);
        }
        ubuf[t] = u;
        if (t == 0) { dbuf[k] = rowb[k]; ebuf[k] = alpha; }
        __syncthreads();

        if (run) {
            double p0 = 0.0, p1 = 0.0;
            #pragma unroll
            for (int j = 0; j < 32; ++j) {
                double2 uv = *(const double2*)&ubuf[2 * j];
                p0 += A[2 * j]     * uv.x;
                p1 += A[2 * j + 1] * uv.y;
            }
            double p = (t > k) ? (p0 + p1) / Kh : 0.0;
            double cc = wsum(u * p) / (2.0 * Kh);
            w = p - cc * u;
        }
        wbuf[t] = w;
        __syncthreads();

        if (run) {
            #pragma unroll
            for (int j = 0; j < 32; ++j) {
                double2 uv = *(const double2*)&ubuf[2 * j];
                double2 wv = *(const double2*)&wbuf[2 * j];
                A[2 * j]     -= u * wv.x + w * uv.x;
                A[2 * j + 1] -= u * wv.y + w * uv.y;
            }
        }
    }

    // ---- loop 2: k = 32..61, active range is [32,64): width-32 static ----
    #pragma unroll 1
    for (int k = 32; k < 62; ++k) {
        if (t == k) {
            #pragma unroll
            for (int j = 16; j < 32; ++j)
                *(double2*)&rowb[2 * j] = double2{A[2 * j], A[2 * j + 1]};
        }
        __syncthreads();

        double s0 = 0.0, s1 = 0.0;
        #pragma unroll
        for (int j = 32; j < 64; ++j) {
            double aj = (j > k) ? A[j] : 0.0;
            if (j & 1) s1 += aj * aj; else s0 += aj * aj;
        }
        double sigma = __shfl(s0 + s1, k, 64);
        double x  = rowb[t];
        double x1 = __shfl(x, k + 1, 64);

        double alpha = 0.0, u = 0.0, w = 0.0, Kh = 1.0;
        bool run = (sigma > 1e-300);
        if (run) {
            double sq = sqrt(sigma);
            alpha = (x1 >= 0.0) ? -sq : sq;
            Kh = sigma - x1 * alpha;
            u = (t == k + 1) ? (x - alpha) : ((t > k) ? x : 0.0);
        }
        ubuf[t] = u;
        if (t == 0) { dbuf[k] = rowb[k]; ebuf[k] = alpha; }
        __syncthreads();

        if (run) {
            double p0 = 0.0, p1 = 0.0;
            #pragma unroll
            for (int j = 16; j < 32; ++j) {
                double2 uv = *(const double2*)&ubuf[2 * j];
                p0 += A[2 * j]     * uv.x;
                p1 += A[2 * j + 1] * uv.y;
            }
            double p = (t > k) ? (p0 + p1) / Kh : 0.0;
            // u*p nonzero only in upper 32 lanes; 5-shfl half-reduction suffices
            double cc = wsum32(u * p) / (2.0 * Kh);
            w = p - cc * u;
        }
        wbuf[t] = w;
        __syncthreads();

        if (run) {
            #pragma unroll
            for (int j = 16; j < 32; ++j) {
                double2 uv = *(const double2*)&ubuf[2 * j];
                double2 wv = *(const double2*)&wbuf[2 * j];
                A[2 * j]     -= u * wv.x + w * uv.x;
                A[2 * j + 1] -= u * wv.y + w * uv.y;
            }
        }
    }

    if (t == 62) dbuf[62] = A[62];
    if (t == 63) { dbuf[63] = A[63]; ebuf[62] = A[62]; }
    if (t == 0)  ebuf[63] = 0.0;
    __syncthreads();

    double* tg = trid + (size_t)g * 128;
    tg[t]      = dbuf[t];
    tg[64 + t] = ebuf[t];
}

// ---------------------------------------------------------------------------
// Kernel 3: bisection (Sturm sign-count) per eigenvalue; descending + log-clip.
// ---------------------------------------------------------------------------
__global__ __launch_bounds__(64) void bisect_kernel(const double* __restrict__ trid,
                                                    float* __restrict__ out)
{
    __shared__ double dd[64];
    __shared__ double e2[64];
    __shared__ double ea[64];

    int g = blockIdx.x;
    int t = threadIdx.x;
    const double* tg = trid + (size_t)g * 128;

    double dv = tg[t];
    double ev = tg[64 + t];
    dd[t] = dv;
    ea[t] = fabs(ev);
    e2[t] = ev * ev;
    __syncthreads();

    double el  = (t > 0) ? ea[t - 1] : 0.0;
    double er  = (t < 63) ? ea[t] : 0.0;
    double rad = el + er;
    double lo = wmin(dv - rad);
    double hi = wmax(dv + rad);
    double mid0 = 0.5 * (lo + hi);
    double half = (0.5 * (hi - lo) + 1e-12) * 1.0000001;
    double a = mid0 - half;
    double b = mid0 + half;

    for (int it = 0; it < 34; ++it) {
        double xm = 0.5 * (a + b);
        double pm = 1.0;
        double p  = dd[0] - xm;
        int cnt = (p < 0.0);
        #pragma unroll
        for (int i = 1; i < 64; ++i) {
            double pi = (dd[i] - xm) * p - e2[i - 1] * pm;
            cnt += ((pi < 0.0) != (p < 0.0));
            double ap = fabs(pi);
            double s = (ap > 1e150) ? 1e-150 : ((ap < 1e-150) ? 1e150 : 1.0);
            pm = p * s;
            p  = pi * s;
        }
        if (cnt > t) b = xm; else a = xm;
    }

    double lam = 0.5 * (a + b);
    double v = fmax(lam, 1e-8);
    out[(size_t)g * 64 + (63 - t)] = (float)log(v);
}

// ---------------------------------------------------------------------------
extern "C" void kernel_launch(void* const* d_in, const int* in_sizes, int n_in,
                              void* d_out, int out_size, void* d_ws, size_t ws_size,
                              hipStream_t stream)
{
    const float* X    = (const float*)d_in[0]; // [2048,2048] fp32
    const float* Wt   = (const float*)d_in[1]; // [4096,2048] fp32
    const float* bias = (const float*)d_in[2]; // [4096] fp32
    const float* regp = (const float*)d_in[3]; // [1] fp32

    char* w = (char*)d_ws;
    float*  M    = (float*)w;                        // 32 MB
    double* trid = (double*)(w + 33554432);          // 2 MB
    float* out = (float*)d_out;                      // [2048,64] fp32

    const size_t NEED_PLANES = 111149056ull;
    if (ws_size >= NEED_PLANES) {
        unsigned short* Xh = (unsigned short*)(w + 35651584);
        unsigned short* Xm = (unsigned short*)(w + 44040192);
        unsigned short* Xl = (unsigned short*)(w + 52428800);
        unsigned short* Wh = (unsigned short*)(w + 60817408);
        unsigned short* Wm = (unsigned short*)(w + 77594624);
        unsigned short* Wl = (unsigned short*)(w + 94371840);
        split_kernel<<<dim3(12288), dim3(256), 0, stream>>>(X, Wt, Xh, Xm, Xl, Wh, Wm, Wl);
        gemm_64<<<dim3(1024), dim3(256), 0, stream>>>(
            Xh, Xm, Xl, Wh, Wm, Wl, bias, M);
    } else {
        gemm_bt<<<dim3(32, 16), dim3(256), 0, stream>>>(X, Wt, bias, M);
    }
    tridiag_kernel<<<dim3(2048), dim3(64), 0, stream>>>(M, regp, trid);
    bisect_kernel<<<dim3(2048), dim3(64), 0, stream>>>(trid, out);
}

// Round 11
// 741.916 us; speedup vs baseline: 2.1036x; 2.1036x over previous
//
#include <hip/hip_runtime.h>

typedef __bf16 bf16x8 __attribute__((ext_vector_type(8)));
typedef float f32x4 __attribute__((ext_vector_type(4)));

union U8 { uint4 u; bf16x8 b; };

__device__ inline float bf16f(unsigned short h) {
    return __uint_as_float(((unsigned)h) << 16);
}

__device__ inline unsigned short f32_to_bf16_rn(float f) {
    unsigned u = __float_as_uint(f);
    unsigned rounding = 0x7FFFu + ((u >> 16) & 1u);
    u += rounding;
    return (unsigned short)(u >> 16);
}

__device__ inline double wsum(double v) {
    #pragma unroll
    for (int m = 32; m; m >>= 1) v += __shfl_xor(v, m, 64);
    return v;
}
__device__ inline double wsum32(double v) {   // reduce within each 32-lane half
    #pragma unroll
    for (int m = 16; m; m >>= 1) v += __shfl_xor(v, m, 64);
    return v;
}
__device__ inline double wmin(double v) {
    #pragma unroll
    for (int m = 32; m; m >>= 1) v = fmin(v, __shfl_xor(v, m, 64));
    return v;
}
__device__ inline double wmax(double v) {
    #pragma unroll
    for (int m = 32; m; m >>= 1) v = fmax(v, __shfl_xor(v, m, 64));
    return v;
}

#define AS1C(p) ((const __attribute__((address_space(1))) void*)(p))
#define AS3(p)  ((__attribute__((address_space(3))) void*)(p))

// ---------------------------------------------------------------------------
// Kernel 0: pre-split fp32 -> 3 bf16 planes (h+m+l) for X and W.
// ---------------------------------------------------------------------------
__global__ __launch_bounds__(256) void split_kernel(
    const float* __restrict__ X, const float* __restrict__ W,
    unsigned short* __restrict__ Xh, unsigned short* __restrict__ Xm, unsigned short* __restrict__ Xl,
    unsigned short* __restrict__ Wh, unsigned short* __restrict__ Wm, unsigned short* __restrict__ Wl)
{
    size_t i4 = (size_t)blockIdx.x * 256 + threadIdx.x;   // float4 index, total 3145728
    const float* src; unsigned short *ph, *pm, *pl; size_t off4;
    if (i4 < 1048576) { src = X; ph = Xh; pm = Xm; pl = Xl; off4 = i4; }
    else              { src = W; ph = Wh; pm = Wm; pl = Wl; off4 = i4 - 1048576; }

    float4 v = ((const float4*)src)[off4];
    ushort4 h, m, l;
    float r1;
    h.x = f32_to_bf16_rn(v.x); r1 = v.x - bf16f(h.x);
    m.x = f32_to_bf16_rn(r1);  l.x = f32_to_bf16_rn(r1 - bf16f(m.x));
    h.y = f32_to_bf16_rn(v.y); r1 = v.y - bf16f(h.y);
    m.y = f32_to_bf16_rn(r1);  l.y = f32_to_bf16_rn(r1 - bf16f(m.y));
    h.z = f32_to_bf16_rn(v.z); r1 = v.z - bf16f(h.z);
    m.z = f32_to_bf16_rn(r1);  l.z = f32_to_bf16_rn(r1 - bf16f(m.z));
    h.w = f32_to_bf16_rn(v.w); r1 = v.w - bf16f(h.w);
    m.w = f32_to_bf16_rn(r1);  l.w = f32_to_bf16_rn(r1 - bf16f(m.w));

    ((ushort4*)ph)[off4] = h;
    ((ushort4*)pm)[off4] = m;
    ((ushort4*)pl)[off4] = l;
}

// ---------------------------------------------------------------------------
// Kernel 1 (v4): 6-plane bf16 GEMM, 128x64 tiles -> 1024 blocks, 36 KB LDS
// -> 4 blocks/CU. Single-buffer global_load_lds width-16, 2-barrier K-loop.
// ---------------------------------------------------------------------------
__global__ __launch_bounds__(256) void gemm_64(
    const unsigned short* __restrict__ Xh, const unsigned short* __restrict__ Xm,
    const unsigned short* __restrict__ Xl,
    const unsigned short* __restrict__ Wh, const unsigned short* __restrict__ Wm,
    const unsigned short* __restrict__ Wl,
    const float* __restrict__ biasf, float* __restrict__ M)
{
    const int K = 2048, N = 4096;
    __shared__ unsigned short S[18432];   // 36 KB

    int tid  = threadIdx.x;
    int id   = blockIdx.x;                 // 0..1023
    int c    = id & 7;                     // XCD (hw round-robins id%8)
    int sid  = id >> 3;                    // 0..127
    int bx   = c * 8 + (sid & 7);          // 0..63
    int by   = sid >> 3;                   // 0..15
    int m0   = by * 128;
    int n0   = bx * 64;

    int wave = tid >> 6;
    int lane = tid & 63;
    int l16  = lane & 15;
    int quad = lane >> 4;
    int wm   = wave * 32;

    const unsigned short* gpA[3];
    const unsigned short* gpB[3];
    gpA[0] = Xh + (size_t)m0 * K;
    gpA[1] = Xm + (size_t)m0 * K;
    gpA[2] = Xl + (size_t)m0 * K;
    gpB[0] = Wh + (size_t)n0 * K;
    gpB[1] = Wm + (size_t)n0 * K;
    gpB[2] = Wl + (size_t)n0 * K;

    int rA = lane >> 2;              // 0..15
    int cA = (lane & 3) << 3;        // ushort col offset 0,8,16,24

    f32x4 acc[2][4];
    #pragma unroll
    for (int mi = 0; mi < 2; ++mi)
        #pragma unroll
        for (int ni = 0; ni < 4; ++ni)
            acc[mi][ni] = f32x4{0.f, 0.f, 0.f, 0.f};

    for (int k0 = 0; k0 < K; k0 += 32) {
        __syncthreads();
        #pragma unroll
        for (int p = 0; p < 3; ++p) {
            #pragma unroll
            for (int q = 0; q < 2; ++q) {
                const unsigned short* g = gpA[p] + (size_t)(32 * wave + 16 * q + rA) * K + k0 + cA;
                char* l = (char*)S + p * 8192 + wave * 2048 + q * 1024;
                __builtin_amdgcn_global_load_lds(AS1C(g), AS3(l), 16, 0, 0);
            }
            {
                const unsigned short* g = gpB[p] + (size_t)(16 * wave + rA) * K + k0 + cA;
                char* l = (char*)S + 24576 + p * 4096 + wave * 1024;
                __builtin_amdgcn_global_load_lds(AS1C(g), AS3(l), 16, 0, 0);
            }
        }
        __syncthreads();

        U8 ah[2], am[2], al[2], bh[4], bm[4], bl[4];
        #pragma unroll
        for (int mi = 0; mi < 2; ++mi) {
            int ro = (wm + mi * 16 + l16) * 32 + quad * 8;
            ah[mi].u = *(const uint4*)&S[ro];
            am[mi].u = *(const uint4*)&S[4096 + ro];
            al[mi].u = *(const uint4*)&S[8192 + ro];
        }
        #pragma unroll
        for (int ni = 0; ni < 4; ++ni) {
            int ro = (ni * 16 + l16) * 32 + quad * 8;
            bh[ni].u = *(const uint4*)&S[12288 + ro];
            bm[ni].u = *(const uint4*)&S[14336 + ro];
            bl[ni].u = *(const uint4*)&S[16384 + ro];
        }

        #pragma unroll
        for (int mi = 0; mi < 2; ++mi)
            #pragma unroll
            for (int ni = 0; ni < 4; ++ni) {
                acc[mi][ni] = __builtin_amdgcn_mfma_f32_16x16x32_bf16(
                    al[mi].b, bh[ni].b, acc[mi][ni], 0, 0, 0);
                acc[mi][ni] = __builtin_amdgcn_mfma_f32_16x16x32_bf16(
                    ah[mi].b, bl[ni].b, acc[mi][ni], 0, 0, 0);
                acc[mi][ni] = __builtin_amdgcn_mfma_f32_16x16x32_bf16(
                    am[mi].b, bm[ni].b, acc[mi][ni], 0, 0, 0);
                acc[mi][ni] = __builtin_amdgcn_mfma_f32_16x16x32_bf16(
                    am[mi].b, bh[ni].b, acc[mi][ni], 0, 0, 0);
                acc[mi][ni] = __builtin_amdgcn_mfma_f32_16x16x32_bf16(
                    ah[mi].b, bm[ni].b, acc[mi][ni], 0, 0, 0);
                acc[mi][ni] = __builtin_amdgcn_mfma_f32_16x16x32_bf16(
                    ah[mi].b, bh[ni].b, acc[mi][ni], 0, 0, 0);
            }
    }

    #pragma unroll
    for (int ni = 0; ni < 4; ++ni) {
        int col = n0 + ni * 16 + l16;
        float bv = biasf[col];
        #pragma unroll
        for (int mi = 0; mi < 2; ++mi) {
            int row = m0 + wm + mi * 16 + quad * 4;
            #pragma unroll
            for (int r = 0; r < 4; ++r)
                M[(size_t)(row + r) * N + col] = acc[mi][ni][r] + bv;
        }
    }
}

// ---------------------------------------------------------------------------
// Kernel 1-fallback: round-3 in-kernel split GEMM (used only if ws too small).
// ---------------------------------------------------------------------------
__global__ __launch_bounds__(256) void gemm_bt(const float* __restrict__ Xf,
                                               const float* __restrict__ Wf,
                                               const float* __restrict__ biasf,
                                               float* __restrict__ M)
{
    const int K = 2048, N = 4096;
    __shared__ unsigned short AsH[128][32];
    __shared__ unsigned short AsM[128][32];
    __shared__ unsigned short AsL[128][32];
    __shared__ unsigned short BsH[128][32];
    __shared__ unsigned short BsM[128][32];
    __shared__ unsigned short BsL[128][32];

    int tid  = threadIdx.x;
    int m0   = blockIdx.y * 128;
    int n0   = blockIdx.x * 128;
    int wid  = tid >> 6;
    int lane = tid & 63;
    int wm   = (wid >> 1) * 64;
    int wn   = (wid & 1) * 64;
    int l16  = lane & 15;
    int quad = lane >> 4;

    f32x4 acc[4][4];
    #pragma unroll
    for (int mi = 0; mi < 4; ++mi)
        #pragma unroll
        for (int ni = 0; ni < 4; ++ni)
            acc[mi][ni] = f32x4{0.f, 0.f, 0.f, 0.f};

    for (int k0 = 0; k0 < K; k0 += 32) {
        #pragma unroll
        for (int s = 0; s < 4; ++s) {
            int c  = tid + s * 256;
            int r  = c >> 3;
            int kc = (c & 7) << 2;
            {
                float4 v = *(const float4*)&Xf[(size_t)(m0 + r) * K + k0 + kc];
                ushort4 h, mm_, l; float r1;
                h.x = f32_to_bf16_rn(v.x); r1 = v.x - bf16f(h.x);
                mm_.x = f32_to_bf16_rn(r1); l.x = f32_to_bf16_rn(r1 - bf16f(mm_.x));
                h.y = f32_to_bf16_rn(v.y); r1 = v.y - bf16f(h.y);
                mm_.y = f32_to_bf16_rn(r1); l.y = f32_to_bf16_rn(r1 - bf16f(mm_.y));
                h.z = f32_to_bf16_rn(v.z); r1 = v.z - bf16f(h.z);
                mm_.z = f32_to_bf16_rn(r1); l.z = f32_to_bf16_rn(r1 - bf16f(mm_.z));
                h.w = f32_to_bf16_rn(v.w); r1 = v.w - bf16f(h.w);
                mm_.w = f32_to_bf16_rn(r1); l.w = f32_to_bf16_rn(r1 - bf16f(mm_.w));
                *(ushort4*)&AsH[r][kc] = h; *(ushort4*)&AsM[r][kc] = mm_; *(ushort4*)&AsL[r][kc] = l;
            }
            {
                float4 v = *(const float4*)&Wf[(size_t)(n0 + r) * K + k0 + kc];
                ushort4 h, mm_, l; float r1;
                h.x = f32_to_bf16_rn(v.x); r1 = v.x - bf16f(h.x);
                mm_.x = f32_to_bf16_rn(r1); l.x = f32_to_bf16_rn(r1 - bf16f(mm_.x));
                h.y = f32_to_bf16_rn(v.y); r1 = v.y - bf16f(h.y);
                mm_.y = f32_to_bf16_rn(r1); l.y = f32_to_bf16_rn(r1 - bf16f(mm_.y));
                h.z = f32_to_bf16_rn(v.z); r1 = v.z - bf16f(h.z);
                mm_.z = f32_to_bf16_rn(r1); l.z = f32_to_bf16_rn(r1 - bf16f(mm_.z));
                h.w = f32_to_bf16_rn(v.w); r1 = v.w - bf16f(h.w);
                mm_.w = f32_to_bf16_rn(r1); l.w = f32_to_bf16_rn(r1 - bf16f(mm_.w));
                *(ushort4*)&BsH[r][kc] = h; *(ushort4*)&BsM[r][kc] = mm_; *(ushort4*)&BsL[r][kc] = l;
            }
        }
        __syncthreads();

        U8 ah[4], am[4], al[4], bh[4], bm[4], bl[4];
        #pragma unroll
        for (int mi = 0; mi < 4; ++mi) {
            ah[mi].u = *(const uint4*)&AsH[wm + mi * 16 + l16][quad * 8];
            am[mi].u = *(const uint4*)&AsM[wm + mi * 16 + l16][quad * 8];
            al[mi].u = *(const uint4*)&AsL[wm + mi * 16 + l16][quad * 8];
        }
        #pragma unroll
        for (int ni = 0; ni < 4; ++ni) {
            bh[ni].u = *(const uint4*)&BsH[wn + ni * 16 + l16][quad * 8];
            bm[ni].u = *(const uint4*)&BsM[wn + ni * 16 + l16][quad * 8];
            bl[ni].u = *(const uint4*)&BsL[wn + ni * 16 + l16][quad * 8];
        }

        #pragma unroll
        for (int mi = 0; mi < 4; ++mi)
            #pragma unroll
            for (int ni = 0; ni < 4; ++ni) {
                acc[mi][ni] = __builtin_amdgcn_mfma_f32_16x16x32_bf16(al[mi].b, bh[ni].b, acc[mi][ni], 0, 0, 0);
                acc[mi][ni] = __builtin_amdgcn_mfma_f32_16x16x32_bf16(ah[mi].b, bl[ni].b, acc[mi][ni], 0, 0, 0);
                acc[mi][ni] = __builtin_amdgcn_mfma_f32_16x16x32_bf16(am[mi].b, bm[ni].b, acc[mi][ni], 0, 0, 0);
                acc[mi][ni] = __builtin_amdgcn_mfma_f32_16x16x32_bf16(am[mi].b, bh[ni].b, acc[mi][ni], 0, 0, 0);
                acc[mi][ni] = __builtin_amdgcn_mfma_f32_16x16x32_bf16(ah[mi].b, bm[ni].b, acc[mi][ni], 0, 0, 0);
                acc[mi][ni] = __builtin_amdgcn_mfma_f32_16x16x32_bf16(ah[mi].b, bh[ni].b, acc[mi][ni], 0, 0, 0);
            }
        __syncthreads();
    }

    #pragma unroll
    for (int ni = 0; ni < 4; ++ni) {
        int col = n0 + wn + ni * 16 + l16;
        float bv = biasf[col];
        #pragma unroll
        for (int mi = 0; mi < 4; ++mi) {
            int row = m0 + wm + mi * 16 + quad * 4;
            #pragma unroll
            for (int r = 0; r < 4; ++r)
                M[(size_t)(row + r) * N + col] = acc[mi][ni][r] + bv;
        }
    }
}

// ---------------------------------------------------------------------------
// Kernel 2 (v6): register-resident fp64 Householder tridiag.
// = v5 body (7 KB LDS 4-phase staging, width-split k-loop) but with
// __launch_bounds__(64,3): VGPR budget 170 >= ~160 needed (A[64]=128 + temps).
// v5's (64,4) capped at 128 -> total spill (R10 post-mortem). 3 waves/SIMD.
// ---------------------------------------------------------------------------
__global__ __launch_bounds__(64, 3) void tridiag_kernel(const float* __restrict__ M,
                                                        const float* __restrict__ regf,
                                                        double* __restrict__ trid)
{
    __shared__ float Ms[16][65];                       // 4.2 KB staging chunk
    __shared__ __align__(16) double rowb[64];
    __shared__ __align__(16) double ubuf[64];
    __shared__ __align__(16) double wbuf[64];
    __shared__ double dbuf[64];
    __shared__ double ebuf[64];

    int g = blockIdx.x;
    int t = threadIdx.x;
    const float* Mg = M + (size_t)g * 4096;

    double A[64];                                      // row t, register-resident
    #pragma unroll
    for (int j = 0; j < 64; ++j) A[j] = 0.0;

    // 4-phase staging + symmetrize: A[j] = 0.5*(M[t][j] + M[j][t])
    #pragma unroll
    for (int ph = 0; ph < 4; ++ph) {
        #pragma unroll
        for (int r = 0; r < 16; ++r)
            Ms[r][t] = Mg[(ph * 16 + r) * 64 + t];     // coalesced
        __syncthreads();
        #pragma unroll
        for (int jj = 0; jj < 16; ++jj)                // column part: M[j][t]
            A[ph * 16 + jj] += 0.5 * (double)Ms[jj][t];
        if ((t >> 4) == ph) {                          // row part: M[t][j]
            int tr = t & 15;
            #pragma unroll
            for (int j = 0; j < 64; ++j)
                A[j] += 0.5 * (double)Ms[tr][j];
        }
        __syncthreads();
    }
    double regv = (double)regf[0];
    #pragma unroll
    for (int j = 0; j < 64; ++j)
        A[j] += (j == t) ? regv : 0.0;

    // ---- loop 1: k = 0..31, full width ----
    #pragma unroll 1
    for (int k = 0; k < 32; ++k) {
        if (t == k) {
            #pragma unroll
            for (int j = 0; j < 32; ++j)
                *(double2*)&rowb[2 * j] = double2{A[2 * j], A[2 * j + 1]};
        }
        __syncthreads();

        double s0 = 0.0, s1 = 0.0;
        #pragma unroll
        for (int j = 0; j < 64; ++j) {
            double aj = (j > k) ? A[j] : 0.0;
            if (j & 1) s1 += aj * aj; else s0 += aj * aj;
        }
        double sigma = __shfl(s0 + s1, k, 64);
        double x  = rowb[t];
        double x1 = __shfl(x, k + 1, 64);

        double alpha = 0.0, u = 0.0, w = 0.0, Kh = 1.0;
        bool run = (sigma > 1e-300);
        if (run) {
            double sq = sqrt(sigma);
            alpha = (x1 >= 0.0) ? -sq : sq;
            Kh = sigma - x1 * alpha;
            u = (t == k + 1) ? (x - alpha) : ((t > k) ? x : 0.0);
        }
        ubuf[t] = u;
        if (t == 0) { dbuf[k] = rowb[k]; ebuf[k] = alpha; }
        __syncthreads();

        if (run) {
            double p0 = 0.0, p1 = 0.0;
            #pragma unroll
            for (int j = 0; j < 32; ++j) {
                double2 uv = *(const double2*)&ubuf[2 * j];
                p0 += A[2 * j]     * uv.x;
                p1 += A[2 * j + 1] * uv.y;
            }
            double p = (t > k) ? (p0 + p1) / Kh : 0.0;
            double cc = wsum(u * p) / (2.0 * Kh);
            w = p - cc * u;
        }
        wbuf[t] = w;
        __syncthreads();

        if (run) {
            #pragma unroll
            for (int j = 0; j < 32; ++j) {
                double2 uv = *(const double2*)&ubuf[2 * j];
                double2 wv = *(const double2*)&wbuf[2 * j];
                A[2 * j]     -= u * wv.x + w * uv.x;
                A[2 * j + 1] -= u * wv.y + w * uv.y;
            }
        }
    }

    // ---- loop 2: k = 32..61, active range is [32,64): width-32 static ----
    #pragma unroll 1
    for (int k = 32; k < 62; ++k) {
        if (t == k) {
            #pragma unroll
            for (int j = 16; j < 32; ++j)
                *(double2*)&rowb[2 * j] = double2{A[2 * j], A[2 * j + 1]};
        }
        __syncthreads();

        double s0 = 0.0, s1 = 0.0;
        #pragma unroll
        for (int j = 32; j < 64; ++j) {
            double aj = (j > k) ? A[j] : 0.0;
            if (j & 1) s1 += aj * aj; else s0 += aj * aj;
        }
        double sigma = __shfl(s0 + s1, k, 64);
        double x  = rowb[t];
        double x1 = __shfl(x, k + 1, 64);

        double alpha = 0.0, u = 0.0, w = 0.0, Kh = 1.0;
        bool run = (sigma > 1e-300);
        if (run) {
            double sq = sqrt(sigma);
            alpha = (x1 >= 0.0) ? -sq : sq;
            Kh = sigma - x1 * alpha;
            u = (t == k + 1) ? (x - alpha) : ((t > k) ? x : 0.0);
        }
        ubuf[t] = u;
        if (t == 0) { dbuf[k] = rowb[k]; ebuf[k] = alpha; }
        __syncthreads();

        if (run) {
            double p0 = 0.0, p1 = 0.0;
            #pragma unroll
            for (int j = 16; j < 32; ++j) {
                double2 uv = *(const double2*)&ubuf[2 * j];
                p0 += A[2 * j]     * uv.x;
                p1 += A[2 * j + 1] * uv.y;
            }
            double p = (t > k) ? (p0 + p1) / Kh : 0.0;
            // u*p nonzero only in upper 32 lanes; 5-shfl half-reduction suffices
            double cc = wsum32(u * p) / (2.0 * Kh);
            w = p - cc * u;
        }
        wbuf[t] = w;
        __syncthreads();

        if (run) {
            #pragma unroll
            for (int j = 16; j < 32; ++j) {
                double2 uv = *(const double2*)&ubuf[2 * j];
                double2 wv = *(const double2*)&wbuf[2 * j];
                A[2 * j]     -= u * wv.x + w * uv.x;
                A[2 * j + 1] -= u * wv.y + w * uv.y;
            }
        }
    }

    if (t == 62) dbuf[62] = A[62];
    if (t == 63) { dbuf[63] = A[63]; ebuf[62] = A[62]; }
    if (t == 0)  ebuf[63] = 0.0;
    __syncthreads();

    double* tg = trid + (size_t)g * 128;
    tg[t]      = dbuf[t];
    tg[64 + t] = ebuf[t];
}

// ---------------------------------------------------------------------------
// Kernel 3: bisection (Sturm sign-count) per eigenvalue; descending + log-clip.
// ---------------------------------------------------------------------------
__global__ __launch_bounds__(64) void bisect_kernel(const double* __restrict__ trid,
                                                    float* __restrict__ out)
{
    __shared__ double dd[64];
    __shared__ double e2[64];
    __shared__ double ea[64];

    int g = blockIdx.x;
    int t = threadIdx.x;
    const double* tg = trid + (size_t)g * 128;

    double dv = tg[t];
    double ev = tg[64 + t];
    dd[t] = dv;
    ea[t] = fabs(ev);
    e2[t] = ev * ev;
    __syncthreads();

    double el  = (t > 0) ? ea[t - 1] : 0.0;
    double er  = (t < 63) ? ea[t] : 0.0;
    double rad = el + er;
    double lo = wmin(dv - rad);
    double hi = wmax(dv + rad);
    double mid0 = 0.5 * (lo + hi);
    double half = (0.5 * (hi - lo) + 1e-12) * 1.0000001;
    double a = mid0 - half;
    double b = mid0 + half;

    for (int it = 0; it < 34; ++it) {
        double xm = 0.5 * (a + b);
        double pm = 1.0;
        double p  = dd[0] - xm;
        int cnt = (p < 0.0);
        #pragma unroll
        for (int i = 1; i < 64; ++i) {
            double pi = (dd[i] - xm) * p - e2[i - 1] * pm;
            cnt += ((pi < 0.0) != (p < 0.0));
            double ap = fabs(pi);
            double s = (ap > 1e150) ? 1e-150 : ((ap < 1e-150) ? 1e150 : 1.0);
            pm = p * s;
            p  = pi * s;
        }
        if (cnt > t) b = xm; else a = xm;
    }

    double lam = 0.5 * (a + b);
    double v = fmax(lam, 1e-8);
    out[(size_t)g * 64 + (63 - t)] = (float)log(v);
}

// ---------------------------------------------------------------------------
extern "C" void kernel_launch(void* const* d_in, const int* in_sizes, int n_in,
                              void* d_out, int out_size, void* d_ws, size_t ws_size,
                              hipStream_t stream)
{
    const float* X    = (const float*)d_in[0]; // [2048,2048] fp32
    const float* Wt   = (const float*)d_in[1]; // [4096,2048] fp32
    const float* bias = (const float*)d_in[2]; // [4096] fp32
    const float* regp = (const float*)d_in[3]; // [1] fp32

    char* w = (char*)d_ws;
    float*  M    = (float*)w;                        // 32 MB
    double* trid = (double*)(w + 33554432);          // 2 MB
    float* out = (float*)d_out;                      // [2048,64] fp32

    const size_t NEED_PLANES = 111149056ull;
    if (ws_size >= NEED_PLANES) {
        unsigned short* Xh = (unsigned short*)(w + 35651584);
        unsigned short* Xm = (unsigned short*)(w + 44040192);
        unsigned short* Xl = (unsigned short*)(w + 52428800);
        unsigned short* Wh = (unsigned short*)(w + 60817408);
        unsigned short* Wm = (unsigned short*)(w + 77594624);
        unsigned short* Wl = (unsigned short*)(w + 94371840);
        split_kernel<<<dim3(12288), dim3(256), 0, stream>>>(X, Wt, Xh, Xm, Xl, Wh, Wm, Wl);
        gemm_64<<<dim3(1024), dim3(256), 0, stream>>>(
            Xh, Xm, Xl, Wh, Wm, Wl, bias, M);
    } else {
        gemm_bt<<<dim3(32, 16), dim3(256), 0, stream>>>(X, Wt, bias, M);
    }
    tridiag_kernel<<<dim3(2048), dim3(64), 0, stream>>>(M, regp, trid);
    bisect_kernel<<<dim3(2048), dim3(64), 0, stream>>>(trid, out);
}

// Round 12
// 740.661 us; speedup vs baseline: 2.1072x; 1.0017x over previous
//
#include <hip/hip_runtime.h>

typedef __bf16 bf16x8 __attribute__((ext_vector_type(8)));
typedef float f32x4 __attribute__((ext_vector_type(4)));

union U8 { uint4 u; bf16x8 b; };

__device__ inline float bf16f(unsigned short h) {
    return __uint_as_float(((unsigned)h) << 16);
}

__device__ inline unsigned short f32_to_bf16_rn(float f) {
    unsigned u = __float_as_uint(f);
    unsigned rounding = 0x7FFFu + ((u >> 16) & 1u);
    u += rounding;
    return (unsigned short)(u >> 16);
}

__device__ inline double wsum(double v) {
    #pragma unroll
    for (int m = 32; m; m >>= 1) v += __shfl_xor(v, m, 64);
    return v;
}
__device__ inline double wmin(double v) {
    #pragma unroll
    for (int m = 32; m; m >>= 1) v = fmin(v, __shfl_xor(v, m, 64));
    return v;
}
__device__ inline double wmax(double v) {
    #pragma unroll
    for (int m = 32; m; m >>= 1) v = fmax(v, __shfl_xor(v, m, 64));
    return v;
}

#define AS1C(p) ((const __attribute__((address_space(1))) void*)(p))
#define AS3(p)  ((__attribute__((address_space(3))) void*)(p))

// ---------------------------------------------------------------------------
// Kernel 0: pre-split fp32 -> 3 bf16 planes (h+m+l) for X and W.
// ---------------------------------------------------------------------------
__global__ __launch_bounds__(256) void split_kernel(
    const float* __restrict__ X, const float* __restrict__ W,
    unsigned short* __restrict__ Xh, unsigned short* __restrict__ Xm, unsigned short* __restrict__ Xl,
    unsigned short* __restrict__ Wh, unsigned short* __restrict__ Wm, unsigned short* __restrict__ Wl)
{
    size_t i4 = (size_t)blockIdx.x * 256 + threadIdx.x;   // float4 index, total 3145728
    const float* src; unsigned short *ph, *pm, *pl; size_t off4;
    if (i4 < 1048576) { src = X; ph = Xh; pm = Xm; pl = Xl; off4 = i4; }
    else              { src = W; ph = Wh; pm = Wm; pl = Wl; off4 = i4 - 1048576; }

    float4 v = ((const float4*)src)[off4];
    ushort4 h, m, l;
    float r1;
    h.x = f32_to_bf16_rn(v.x); r1 = v.x - bf16f(h.x);
    m.x = f32_to_bf16_rn(r1);  l.x = f32_to_bf16_rn(r1 - bf16f(m.x));
    h.y = f32_to_bf16_rn(v.y); r1 = v.y - bf16f(h.y);
    m.y = f32_to_bf16_rn(r1);  l.y = f32_to_bf16_rn(r1 - bf16f(m.y));
    h.z = f32_to_bf16_rn(v.z); r1 = v.z - bf16f(h.z);
    m.z = f32_to_bf16_rn(r1);  l.z = f32_to_bf16_rn(r1 - bf16f(m.z));
    h.w = f32_to_bf16_rn(v.w); r1 = v.w - bf16f(h.w);
    m.w = f32_to_bf16_rn(r1);  l.w = f32_to_bf16_rn(r1 - bf16f(m.w));

    ((ushort4*)ph)[off4] = h;
    ((ushort4*)pm)[off4] = m;
    ((ushort4*)pl)[off4] = l;
}

// ---------------------------------------------------------------------------
// Kernel 1 (v4): 6-plane bf16 GEMM, 128x64 tiles -> 1024 blocks, 36 KB LDS
// -> 4 blocks/CU. Single-buffer global_load_lds width-16, 2-barrier K-loop.
// ---------------------------------------------------------------------------
__global__ __launch_bounds__(256) void gemm_64(
    const unsigned short* __restrict__ Xh, const unsigned short* __restrict__ Xm,
    const unsigned short* __restrict__ Xl,
    const unsigned short* __restrict__ Wh, const unsigned short* __restrict__ Wm,
    const unsigned short* __restrict__ Wl,
    const float* __restrict__ biasf, float* __restrict__ M)
{
    const int K = 2048, N = 4096;
    __shared__ unsigned short S[18432];   // 36 KB

    int tid  = threadIdx.x;
    int id   = blockIdx.x;                 // 0..1023
    int c    = id & 7;                     // XCD (hw round-robins id%8)
    int sid  = id >> 3;                    // 0..127
    int bx   = c * 8 + (sid & 7);          // 0..63
    int by   = sid >> 3;                   // 0..15
    int m0   = by * 128;
    int n0   = bx * 64;

    int wave = tid >> 6;
    int lane = tid & 63;
    int l16  = lane & 15;
    int quad = lane >> 4;
    int wm   = wave * 32;

    const unsigned short* gpA[3];
    const unsigned short* gpB[3];
    gpA[0] = Xh + (size_t)m0 * K;
    gpA[1] = Xm + (size_t)m0 * K;
    gpA[2] = Xl + (size_t)m0 * K;
    gpB[0] = Wh + (size_t)n0 * K;
    gpB[1] = Wm + (size_t)n0 * K;
    gpB[2] = Wl + (size_t)n0 * K;

    int rA = lane >> 2;              // 0..15
    int cA = (lane & 3) << 3;        // ushort col offset 0,8,16,24

    f32x4 acc[2][4];
    #pragma unroll
    for (int mi = 0; mi < 2; ++mi)
        #pragma unroll
        for (int ni = 0; ni < 4; ++ni)
            acc[mi][ni] = f32x4{0.f, 0.f, 0.f, 0.f};

    for (int k0 = 0; k0 < K; k0 += 32) {
        __syncthreads();
        #pragma unroll
        for (int p = 0; p < 3; ++p) {
            #pragma unroll
            for (int q = 0; q < 2; ++q) {
                const unsigned short* g = gpA[p] + (size_t)(32 * wave + 16 * q + rA) * K + k0 + cA;
                char* l = (char*)S + p * 8192 + wave * 2048 + q * 1024;
                __builtin_amdgcn_global_load_lds(AS1C(g), AS3(l), 16, 0, 0);
            }
            {
                const unsigned short* g = gpB[p] + (size_t)(16 * wave + rA) * K + k0 + cA;
                char* l = (char*)S + 24576 + p * 4096 + wave * 1024;
                __builtin_amdgcn_global_load_lds(AS1C(g), AS3(l), 16, 0, 0);
            }
        }
        __syncthreads();

        U8 ah[2], am[2], al[2], bh[4], bm[4], bl[4];
        #pragma unroll
        for (int mi = 0; mi < 2; ++mi) {
            int ro = (wm + mi * 16 + l16) * 32 + quad * 8;
            ah[mi].u = *(const uint4*)&S[ro];
            am[mi].u = *(const uint4*)&S[4096 + ro];
            al[mi].u = *(const uint4*)&S[8192 + ro];
        }
        #pragma unroll
        for (int ni = 0; ni < 4; ++ni) {
            int ro = (ni * 16 + l16) * 32 + quad * 8;
            bh[ni].u = *(const uint4*)&S[12288 + ro];
            bm[ni].u = *(const uint4*)&S[14336 + ro];
            bl[ni].u = *(const uint4*)&S[16384 + ro];
        }

        #pragma unroll
        for (int mi = 0; mi < 2; ++mi)
            #pragma unroll
            for (int ni = 0; ni < 4; ++ni) {
                acc[mi][ni] = __builtin_amdgcn_mfma_f32_16x16x32_bf16(
                    al[mi].b, bh[ni].b, acc[mi][ni], 0, 0, 0);
                acc[mi][ni] = __builtin_amdgcn_mfma_f32_16x16x32_bf16(
                    ah[mi].b, bl[ni].b, acc[mi][ni], 0, 0, 0);
                acc[mi][ni] = __builtin_amdgcn_mfma_f32_16x16x32_bf16(
                    am[mi].b, bm[ni].b, acc[mi][ni], 0, 0, 0);
                acc[mi][ni] = __builtin_amdgcn_mfma_f32_16x16x32_bf16(
                    am[mi].b, bh[ni].b, acc[mi][ni], 0, 0, 0);
                acc[mi][ni] = __builtin_amdgcn_mfma_f32_16x16x32_bf16(
                    ah[mi].b, bm[ni].b, acc[mi][ni], 0, 0, 0);
                acc[mi][ni] = __builtin_amdgcn_mfma_f32_16x16x32_bf16(
                    ah[mi].b, bh[ni].b, acc[mi][ni], 0, 0, 0);
            }
    }

    #pragma unroll
    for (int ni = 0; ni < 4; ++ni) {
        int col = n0 + ni * 16 + l16;
        float bv = biasf[col];
        #pragma unroll
        for (int mi = 0; mi < 2; ++mi) {
            int row = m0 + wm + mi * 16 + quad * 4;
            #pragma unroll
            for (int r = 0; r < 4; ++r)
                M[(size_t)(row + r) * N + col] = acc[mi][ni][r] + bv;
        }
    }
}

// ---------------------------------------------------------------------------
// Kernel 1-fallback: round-3 in-kernel split GEMM (used only if ws too small).
// ---------------------------------------------------------------------------
__global__ __launch_bounds__(256) void gemm_bt(const float* __restrict__ Xf,
                                               const float* __restrict__ Wf,
                                               const float* __restrict__ biasf,
                                               float* __restrict__ M)
{
    const int K = 2048, N = 4096;
    __shared__ unsigned short AsH[128][32];
    __shared__ unsigned short AsM[128][32];
    __shared__ unsigned short AsL[128][32];
    __shared__ unsigned short BsH[128][32];
    __shared__ unsigned short BsM[128][32];
    __shared__ unsigned short BsL[128][32];

    int tid  = threadIdx.x;
    int m0   = blockIdx.y * 128;
    int n0   = blockIdx.x * 128;
    int wid  = tid >> 6;
    int lane = tid & 63;
    int wm   = (wid >> 1) * 64;
    int wn   = (wid & 1) * 64;
    int l16  = lane & 15;
    int quad = lane >> 4;

    f32x4 acc[4][4];
    #pragma unroll
    for (int mi = 0; mi < 4; ++mi)
        #pragma unroll
        for (int ni = 0; ni < 4; ++ni)
            acc[mi][ni] = f32x4{0.f, 0.f, 0.f, 0.f};

    for (int k0 = 0; k0 < K; k0 += 32) {
        #pragma unroll
        for (int s = 0; s < 4; ++s) {
            int c  = tid + s * 256;
            int r  = c >> 3;
            int kc = (c & 7) << 2;
            {
                float4 v = *(const float4*)&Xf[(size_t)(m0 + r) * K + k0 + kc];
                ushort4 h, mm_, l; float r1;
                h.x = f32_to_bf16_rn(v.x); r1 = v.x - bf16f(h.x);
                mm_.x = f32_to_bf16_rn(r1); l.x = f32_to_bf16_rn(r1 - bf16f(mm_.x));
                h.y = f32_to_bf16_rn(v.y); r1 = v.y - bf16f(h.y);
                mm_.y = f32_to_bf16_rn(r1); l.y = f32_to_bf16_rn(r1 - bf16f(mm_.y));
                h.z = f32_to_bf16_rn(v.z); r1 = v.z - bf16f(h.z);
                mm_.z = f32_to_bf16_rn(r1); l.z = f32_to_bf16_rn(r1 - bf16f(mm_.z));
                h.w = f32_to_bf16_rn(v.w); r1 = v.w - bf16f(h.w);
                mm_.w = f32_to_bf16_rn(r1); l.w = f32_to_bf16_rn(r1 - bf16f(mm_.w));
                *(ushort4*)&AsH[r][kc] = h; *(ushort4*)&AsM[r][kc] = mm_; *(ushort4*)&AsL[r][kc] = l;
            }
            {
                float4 v = *(const float4*)&Wf[(size_t)(n0 + r) * K + k0 + kc];
                ushort4 h, mm_, l; float r1;
                h.x = f32_to_bf16_rn(v.x); r1 = v.x - bf16f(h.x);
                mm_.x = f32_to_bf16_rn(r1); l.x = f32_to_bf16_rn(r1 - bf16f(mm_.x));
                h.y = f32_to_bf16_rn(v.y); r1 = v.y - bf16f(h.y);
                mm_.y = f32_to_bf16_rn(r1); l.y = f32_to_bf16_rn(r1 - bf16f(mm_.y));
                h.z = f32_to_bf16_rn(v.z); r1 = v.z - bf16f(h.z);
                mm_.z = f32_to_bf16_rn(r1); l.z = f32_to_bf16_rn(r1 - bf16f(mm_.z));
                h.w = f32_to_bf16_rn(v.w); r1 = v.w - bf16f(h.w);
                mm_.w = f32_to_bf16_rn(r1); l.w = f32_to_bf16_rn(r1 - bf16f(mm_.w));
                *(ushort4*)&BsH[r][kc] = h; *(ushort4*)&BsM[r][kc] = mm_; *(ushort4*)&BsL[r][kc] = l;
            }
        }
        __syncthreads();

        U8 ah[4], am[4], al[4], bh[4], bm[4], bl[4];
        #pragma unroll
        for (int mi = 0; mi < 4; ++mi) {
            ah[mi].u = *(const uint4*)&AsH[wm + mi * 16 + l16][quad * 8];
            am[mi].u = *(const uint4*)&AsM[wm + mi * 16 + l16][quad * 8];
            al[mi].u = *(const uint4*)&AsL[wm + mi * 16 + l16][quad * 8];
        }
        #pragma unroll
        for (int ni = 0; ni < 4; ++ni) {
            bh[ni].u = *(const uint4*)&BsH[wn + ni * 16 + l16][quad * 8];
            bm[ni].u = *(const uint4*)&BsM[wn + ni * 16 + l16][quad * 8];
            bl[ni].u = *(const uint4*)&BsL[wn + ni * 16 + l16][quad * 8];
        }

        #pragma unroll
        for (int mi = 0; mi < 4; ++mi)
            #pragma unroll
            for (int ni = 0; ni < 4; ++ni) {
                acc[mi][ni] = __builtin_amdgcn_mfma_f32_16x16x32_bf16(al[mi].b, bh[ni].b, acc[mi][ni], 0, 0, 0);
                acc[mi][ni] = __builtin_amdgcn_mfma_f32_16x16x32_bf16(ah[mi].b, bl[ni].b, acc[mi][ni], 0, 0, 0);
                acc[mi][ni] = __builtin_amdgcn_mfma_f32_16x16x32_bf16(am[mi].b, bm[ni].b, acc[mi][ni], 0, 0, 0);
                acc[mi][ni] = __builtin_amdgcn_mfma_f32_16x16x32_bf16(am[mi].b, bh[ni].b, acc[mi][ni], 0, 0, 0);
                acc[mi][ni] = __builtin_amdgcn_mfma_f32_16x16x32_bf16(ah[mi].b, bm[ni].b, acc[mi][ni], 0, 0, 0);
                acc[mi][ni] = __builtin_amdgcn_mfma_f32_16x16x32_bf16(ah[mi].b, bh[ni].b, acc[mi][ni], 0, 0, 0);
            }
        __syncthreads();
    }

    #pragma unroll
    for (int ni = 0; ni < 4; ++ni) {
        int col = n0 + wn + ni * 16 + l16;
        float bv = biasf[col];
        #pragma unroll
        for (int mi = 0; mi < 4; ++mi) {
            int row = m0 + wm + mi * 16 + quad * 4;
            #pragma unroll
            for (int r = 0; r < 4; ++r)
                M[(size_t)(row + r) * N + col] = acc[mi][ni][r] + bv;
        }
    }
}

// ---------------------------------------------------------------------------
// Kernel 2 (v7): fp64 Householder tridiag, row SPLIT ACROSS TWO WAVES.
// Block = 128 threads: wave 0 holds cols 0..31 of all rows, wave 1 cols
// 32..63. Per-thread R[32] = 64 regs (+~25 temps) -> fits 128-reg cap of
// __launch_bounds__(128,4) -> 4 waves/SIMD (2x v6). sigma & c computed
// wave-redundantly (6-shfl wsum, no cross-wave exchange); A*u dot exchanges
// one partial through LDS. Column k = the two r==k threads dump halves.
// ---------------------------------------------------------------------------
__global__ __launch_bounds__(128, 4) void tridiag_kernel(const float* __restrict__ M,
                                                         const float* __restrict__ regf,
                                                         double* __restrict__ trid)
{
    __shared__ float Ms[64][65];                     // 16.6 KB staging
    __shared__ __align__(16) double colk[64];
    __shared__ __align__(16) double ubuf[64];
    __shared__ __align__(16) double wbuf[64];
    __shared__ __align__(16) double partial[128];
    __shared__ double dbuf[64];
    __shared__ double ebuf[64];

    int g   = blockIdx.x;
    int tid = threadIdx.x;
    int w   = tid >> 6;          // half: 0 -> cols 0..31, 1 -> cols 32..63
    int r   = tid & 63;          // row
    int c0  = w * 32;
    const float* Mg = M + (size_t)g * 4096;

    for (int i = tid; i < 4096; i += 128)
        Ms[i >> 6][i & 63] = Mg[i];                  // coalesced
    __syncthreads();

    double R[32];                                    // row r, cols c0..c0+31
    double regv = (double)regf[0];
    #pragma unroll
    for (int jj = 0; jj < 32; ++jj) {
        int j = c0 + jj;
        R[jj] = 0.5 * ((double)Ms[r][j] + (double)Ms[j][r]);
    }
    #pragma unroll
    for (int jj = 0; jj < 32; ++jj)
        R[jj] += (c0 + jj == r) ? regv : 0.0;        // static reg index

    #pragma unroll 1
    for (int k = 0; k < 62; ++k) {
        if (r == k) {                                // row k final: dump halves
            #pragma unroll
            for (int jj = 0; jj < 16; ++jj)
                *(double2*)&colk[c0 + 2 * jj] = double2{R[2 * jj], R[2 * jj + 1]};
        }
        __syncthreads();

        double x  = colk[r];
        double xt = (r > k) ? x : 0.0;
        double sigma = wsum(xt * xt);                // wave-redundant, identical
        double x1 = __shfl(x, k + 1, 64);

        double alpha = 0.0, u = 0.0, wv = 0.0, Kh = 1.0;
        bool run = (sigma > 1e-300);
        if (run) {
            double sq = sqrt(sigma);
            alpha = (x1 >= 0.0) ? -sq : sq;
            Kh = sigma - x1 * alpha;                 // = u^T u / 2 > 0
            u = (r == k + 1) ? (x - alpha) : xt;
        }
        if (w == 0) ubuf[r] = u;
        if (tid == 0) { dbuf[k] = colk[k]; ebuf[k] = alpha; }
        __syncthreads();

        double pp = 0.0;
        if (run) {
            double p0 = 0.0, p1 = 0.0;
            #pragma unroll
            for (int jj = 0; jj < 16; ++jj) {
                double2 uv = *(const double2*)&ubuf[c0 + 2 * jj];
                p0 += R[2 * jj]     * uv.x;
                p1 += R[2 * jj + 1] * uv.y;
            }
            pp = p0 + p1;
        }
        partial[w * 64 + r] = pp;
        __syncthreads();

        if (run) {
            double p = (r > k) ? (partial[r] + partial[64 + r]) / Kh : 0.0;
            double cc = wsum(u * p) / (2.0 * Kh);    // wave-redundant, identical
            wv = p - cc * u;
        }
        if (w == 0) wbuf[r] = wv;
        __syncthreads();

        if (run) {
            #pragma unroll
            for (int jj = 0; jj < 16; ++jj) {
                double2 uv = *(const double2*)&ubuf[c0 + 2 * jj];
                double2 wq = *(const double2*)&wbuf[c0 + 2 * jj];
                R[2 * jj]     -= u * wq.x + wv * uv.x;
                R[2 * jj + 1] -= u * wq.y + wv * uv.y;
            }
        }
    }

    if (w == 1 && r == 62) dbuf[62] = R[30];                       // A[62][62]
    if (w == 1 && r == 63) { dbuf[63] = R[31]; ebuf[62] = R[30]; } // A[63][63], A[63][62]
    if (tid == 0) ebuf[63] = 0.0;
    __syncthreads();

    double* tg = trid + (size_t)g * 128;
    if (tid < 64) tg[tid] = dbuf[tid];
    else          tg[64 + (tid - 64)] = ebuf[tid - 64];
}

// ---------------------------------------------------------------------------
// Kernel 3: bisection (Sturm sign-count) per eigenvalue; descending + log-clip.
// ---------------------------------------------------------------------------
__global__ __launch_bounds__(64) void bisect_kernel(const double* __restrict__ trid,
                                                    float* __restrict__ out)
{
    __shared__ double dd[64];
    __shared__ double e2[64];
    __shared__ double ea[64];

    int g = blockIdx.x;
    int t = threadIdx.x;
    const double* tg = trid + (size_t)g * 128;

    double dv = tg[t];
    double ev = tg[64 + t];
    dd[t] = dv;
    ea[t] = fabs(ev);
    e2[t] = ev * ev;
    __syncthreads();

    double el  = (t > 0) ? ea[t - 1] : 0.0;
    double er  = (t < 63) ? ea[t] : 0.0;
    double rad = el + er;
    double lo = wmin(dv - rad);
    double hi = wmax(dv + rad);
    double mid0 = 0.5 * (lo + hi);
    double half = (0.5 * (hi - lo) + 1e-12) * 1.0000001;
    double a = mid0 - half;
    double b = mid0 + half;

    for (int it = 0; it < 34; ++it) {
        double xm = 0.5 * (a + b);
        double pm = 1.0;
        double p  = dd[0] - xm;
        int cnt = (p < 0.0);
        #pragma unroll
        for (int i = 1; i < 64; ++i) {
            double pi = (dd[i] - xm) * p - e2[i - 1] * pm;
            cnt += ((pi < 0.0) != (p < 0.0));
            double ap = fabs(pi);
            double s = (ap > 1e150) ? 1e-150 : ((ap < 1e-150) ? 1e150 : 1.0);
            pm = p * s;
            p  = pi * s;
        }
        if (cnt > t) b = xm; else a = xm;
    }

    double lam = 0.5 * (a + b);
    double v = fmax(lam, 1e-8);
    out[(size_t)g * 64 + (63 - t)] = (float)log(v);
}

// ---------------------------------------------------------------------------
extern "C" void kernel_launch(void* const* d_in, const int* in_sizes, int n_in,
                              void* d_out, int out_size, void* d_ws, size_t ws_size,
                              hipStream_t stream)
{
    const float* X    = (const float*)d_in[0]; // [2048,2048] fp32
    const float* Wt   = (const float*)d_in[1]; // [4096,2048] fp32
    const float* bias = (const float*)d_in[2]; // [4096] fp32
    const float* regp = (const float*)d_in[3]; // [1] fp32

    char* w = (char*)d_ws;
    float*  M    = (float*)w;                        // 32 MB
    double* trid = (double*)(w + 33554432);          // 2 MB
    float* out = (float*)d_out;                      // [2048,64] fp32

    const size_t NEED_PLANES = 111149056ull;
    if (ws_size >= NEED_PLANES) {
        unsigned short* Xh = (unsigned short*)(w + 35651584);
        unsigned short* Xm = (unsigned short*)(w + 44040192);
        unsigned short* Xl = (unsigned short*)(w + 52428800);
        unsigned short* Wh = (unsigned short*)(w + 60817408);
        unsigned short* Wm = (unsigned short*)(w + 77594624);
        unsigned short* Wl = (unsigned short*)(w + 94371840);
        split_kernel<<<dim3(12288), dim3(256), 0, stream>>>(X, Wt, Xh, Xm, Xl, Wh, Wm, Wl);
        gemm_64<<<dim3(1024), dim3(256), 0, stream>>>(
            Xh, Xm, Xl, Wh, Wm, Wl, bias, M);
    } else {
        gemm_bt<<<dim3(32, 16), dim3(256), 0, stream>>>(X, Wt, bias, M);
    }
    tridiag_kernel<<<dim3(2048), dim3(128), 0, stream>>>(M, regp, trid);
    bisect_kernel<<<dim3(2048), dim3(64), 0, stream>>>(trid, out);
}